// Round 2
// baseline (549.864 us; speedup 1.0000x reference)
//
#include <hip/hip_runtime.h>
#include <hip/hip_bf16.h>

#define B64   64
#define DH    512
#define HID   4096
#define VOC   50257
#define NSTEP 4

typedef __attribute__((ext_vector_type(8))) short bf16x8;   // 8 bf16 = 4 VGPRs
typedef __attribute__((ext_vector_type(4))) float f32x4;
typedef __hip_bfloat16 bf16;

__device__ __forceinline__ bf16x8 ldg8(const bf16* p) {
    return *reinterpret_cast<const bf16x8*>(p);
}
__device__ __forceinline__ short f2bf(float x) {
    bf16 h = __float2bfloat16(x);
    return *reinterpret_cast<short*>(&h);
}
// load 8 consecutive f32, round to bf16 fragment
__device__ __forceinline__ bf16x8 cvt8(const float* p) {
    f32x4 a = *reinterpret_cast<const f32x4*>(p);
    f32x4 b = *reinterpret_cast<const f32x4*>(p + 4);
    bf16x8 r;
    r[0] = f2bf(a[0]); r[1] = f2bf(a[1]); r[2] = f2bf(a[2]); r[3] = f2bf(a[3]);
    r[4] = f2bf(b[0]); r[5] = f2bf(b[1]); r[6] = f2bf(b[2]); r[7] = f2bf(b[3]);
    return r;
}
__device__ __forceinline__ float sigmf(float x) { return 1.f / (1.f + __expf(-x)); }

// ---------------------------------------------------------------------------
// Kernel A: h0 = hs(64x4096 f32) @ ip_w(512x4096 f32)^T + ip_b -> both states
// grid 32 x 256 (128 waves: 4 m-tiles x 32 d-tiles)
// ---------------------------------------------------------------------------
__global__ __launch_bounds__(256) void k_proj(
    const float* __restrict__ hs, const float* __restrict__ ipw, const float* __restrict__ ipb,
    float* __restrict__ h0f, float* __restrict__ h1f,
    bf16* __restrict__ h0b, bf16* __restrict__ h1b)
{
    int wid  = blockIdx.x * 4 + (threadIdx.x >> 6);
    int lane = threadIdx.x & 63;
    int lr = lane & 15, q = lane >> 4;
    int m0 = (wid >> 5) * 16;
    int n0 = (wid & 31) * 16;
    const float* arow = hs  + (size_t)(m0 + lr) * HID + q * 8;
    const float* brow = ipw + (size_t)(n0 + lr) * HID + q * 8;
    f32x4 acc = {0.f, 0.f, 0.f, 0.f};
    for (int k0 = 0; k0 < HID; k0 += 32) {
        bf16x8 a = cvt8(arow + k0);
        bf16x8 b = cvt8(brow + k0);
        acc = __builtin_amdgcn_mfma_f32_16x16x32_bf16(a, b, acc, 0, 0, 0);
    }
    int d = n0 + lr;
    float bias = ipb[d];
#pragma unroll
    for (int r = 0; r < 4; ++r) {
        int m = m0 + q * 4 + r;          // C/D: col = lane&15, row = q*4+r
        float v = acc[r] + bias;
        int idx = m * DH + d;
        h0f[idx] = v; h1f[idx] = v;
        bf16 vb = __float2bfloat16(v);
        h0b[idx] = vb; h1b[idx] = vb;
    }
}

// ---------------------------------------------------------------------------
// Kernel B: one GRU cell. gi = x@w_ih^T + b_ih ; gh = h@w_hh^T + b_hh
// r=sig(ir+hr) z=sig(iz+hz) n=tanh(in + r*hn) h'=(1-z)n+z*h
// x comes either from f32 embed rows (xf + ids gather) or from an internal
// bf16 matrix (xb), or is zero (both null). Weights/biases f32, state f32.
// grid 32 x 256
// ---------------------------------------------------------------------------
__global__ __launch_bounds__(256) void k_gru(
    const float* __restrict__ xf, const bf16* __restrict__ xb, const int* __restrict__ ids,
    const float* __restrict__ hf, const bf16* __restrict__ hb,
    const float* __restrict__ wih, const float* __restrict__ whh,
    const float* __restrict__ bih, const float* __restrict__ bhh,
    float* __restrict__ hof, bf16* __restrict__ hob,
    bf16* __restrict__ hbig, int step)
{
    int wid  = blockIdx.x * 4 + (threadIdx.x >> 6);
    int lane = threadIdx.x & 63;
    int lr = lane & 15, q = lane >> 4;
    int m0 = (wid >> 5) * 16;
    int d0 = (wid & 31) * 16;
    int rowb = m0 + lr;

    const float* xfrow = nullptr;
    const bf16*  xbrow = nullptr;
    if (xf) {
        int rid = ids ? ids[rowb * NSTEP] : rowb;
        xfrow = xf + (size_t)rid * DH + q * 8;
    } else if (xb) {
        xbrow = xb + (size_t)rowb * DH + q * 8;
    }
    bool has_x = (xfrow != nullptr) || (xbrow != nullptr);

    const bf16*  hrow = hb + (size_t)rowb * DH + q * 8;
    const float* wiR = wih + (size_t)(0 * DH + d0 + lr) * DH + q * 8;
    const float* wiZ = wih + (size_t)(1 * DH + d0 + lr) * DH + q * 8;
    const float* wiN = wih + (size_t)(2 * DH + d0 + lr) * DH + q * 8;
    const float* whR = whh + (size_t)(0 * DH + d0 + lr) * DH + q * 8;
    const float* whZ = whh + (size_t)(1 * DH + d0 + lr) * DH + q * 8;
    const float* whN = whh + (size_t)(2 * DH + d0 + lr) * DH + q * 8;

    f32x4 aiR = {0,0,0,0}, aiZ = {0,0,0,0}, aiN = {0,0,0,0};
    f32x4 ahR = {0,0,0,0}, ahZ = {0,0,0,0}, ahN = {0,0,0,0};
    for (int k0 = 0; k0 < DH; k0 += 32) {
        bf16x8 ah = ldg8(hrow + k0);
        ahR = __builtin_amdgcn_mfma_f32_16x16x32_bf16(ah, cvt8(whR + k0), ahR, 0, 0, 0);
        ahZ = __builtin_amdgcn_mfma_f32_16x16x32_bf16(ah, cvt8(whZ + k0), ahZ, 0, 0, 0);
        ahN = __builtin_amdgcn_mfma_f32_16x16x32_bf16(ah, cvt8(whN + k0), ahN, 0, 0, 0);
        if (has_x) {
            bf16x8 ax = xfrow ? cvt8(xfrow + k0) : ldg8(xbrow + k0);
            aiR = __builtin_amdgcn_mfma_f32_16x16x32_bf16(ax, cvt8(wiR + k0), aiR, 0, 0, 0);
            aiZ = __builtin_amdgcn_mfma_f32_16x16x32_bf16(ax, cvt8(wiZ + k0), aiZ, 0, 0, 0);
            aiN = __builtin_amdgcn_mfma_f32_16x16x32_bf16(ax, cvt8(wiN + k0), aiN, 0, 0, 0);
        }
    }

    int d = d0 + lr;
    float biR = bih[d], biZ = bih[DH + d], biN = bih[2 * DH + d];
    float bhR = bhh[d], bhZ = bhh[DH + d], bhN = bhh[2 * DH + d];
#pragma unroll
    for (int r = 0; r < 4; ++r) {
        int b = m0 + q * 4 + r;
        float ir = aiR[r] + biR, hr = ahR[r] + bhR;
        float iz = aiZ[r] + biZ, hz = ahZ[r] + bhZ;
        float in_ = aiN[r] + biN, hn = ahN[r] + bhN;
        float rg = sigmf(ir + hr);
        float zg = sigmf(iz + hz);
        float ng = tanhf(in_ + rg * hn);
        float hp = hf[b * DH + d];
        float hv = (1.f - zg) * ng + zg * hp;
        hof[b * DH + d] = hv;
        bf16 hvb = __float2bfloat16(hv);
        hob[b * DH + d] = hvb;
        if (hbig) hbig[(size_t)(b * NSTEP + step) * DH + d] = hvb;
    }
}

// ---------------------------------------------------------------------------
// Kernel C: logits = Hbig(256x512 bf16) @ out_w(50257x512 f32)^T -> out f32
// Hbig rows are m = b*4+step so output index is just m*VOC + v.
// Block = 4 waves, 64 vocab cols/block, all 256 M rows via LDS-staged A.
// LDS row stride 72 bf16 (+8 pad) -> 2-way bank aliasing only (free).
// ---------------------------------------------------------------------------
#define BK 64
#define LDST 72
__global__ __launch_bounds__(256) void k_logits(
    const bf16* __restrict__ hbig, const float* __restrict__ outw, float* __restrict__ out)
{
    __shared__ __align__(16) bf16 sA[256 * LDST];
    int t = threadIdx.x;
    int w = t >> 6, lane = t & 63;
    int lr = lane & 15, q = lane >> 4;
    int n = blockIdx.x * 64 + w * 16 + lr;
    int nr = n < VOC ? n : VOC - 1;
    const float* brow = outw + (size_t)nr * DH + q * 8;

    f32x4 acc[16];
#pragma unroll
    for (int i = 0; i < 16; ++i) acc[i] = (f32x4){0.f, 0.f, 0.f, 0.f};

    for (int k0 = 0; k0 < DH; k0 += BK) {
        // stage A[0:256][k0:k0+64] -> LDS
#pragma unroll
        for (int i = 0; i < 8; ++i) {
            int c = i * 256 + t;
            int m = c >> 3, koff = (c & 7) * 8;
            *reinterpret_cast<bf16x8*>(&sA[m * LDST + koff]) =
                ldg8(hbig + (size_t)m * DH + k0 + koff);
        }
        __syncthreads();
#pragma unroll
        for (int kk = 0; kk < BK; kk += 32) {
            bf16x8 bfrag = cvt8(brow + k0 + kk);
#pragma unroll
            for (int mt = 0; mt < 16; ++mt) {
                bf16x8 afrag = *reinterpret_cast<const bf16x8*>(
                    &sA[(mt * 16 + lr) * LDST + kk + q * 8]);
                acc[mt] = __builtin_amdgcn_mfma_f32_16x16x32_bf16(afrag, bfrag, acc[mt], 0, 0, 0);
            }
        }
        __syncthreads();
    }
    if (n < VOC) {
#pragma unroll
        for (int mt = 0; mt < 16; ++mt) {
#pragma unroll
            for (int r = 0; r < 4; ++r) {
                int m = mt * 16 + q * 4 + r;
                out[(size_t)m * VOC + n] = acc[mt][r];
            }
        }
    }
}

// ---------------------------------------------------------------------------
extern "C" void kernel_launch(void* const* d_in, const int* in_sizes, int n_in,
                              void* d_out, int out_size, void* d_ws, size_t ws_size,
                              hipStream_t stream) {
    const float* hs   = (const float*)d_in[0];
    const int*   tids = (const int*)d_in[1];
    const float* ipw  = (const float*)d_in[2];
    const float* ipb  = (const float*)d_in[3];
    const float* wih0 = (const float*)d_in[4];
    const float* whh0 = (const float*)d_in[5];
    const float* bih0 = (const float*)d_in[6];
    const float* bhh0 = (const float*)d_in[7];
    const float* wih1 = (const float*)d_in[8];
    const float* whh1 = (const float*)d_in[9];
    const float* bih1 = (const float*)d_in[10];
    const float* bhh1 = (const float*)d_in[11];
    const float* embed = (const float*)d_in[12];
    const float* outw  = (const float*)d_in[13];
    float* out = (float*)d_out;

    char* ws = (char*)d_ws;
    float* h0f = (float*)(ws + 0);        // [2][64*512] f32
    float* h1f = (float*)(ws + 262144);   // [2][64*512] f32
    bf16*  h0b = (bf16*)(ws + 524288);    // [2][64*512] bf16
    bf16*  h1b = (bf16*)(ws + 655360);    // [2][64*512] bf16
    bf16*  hbig = (bf16*)(ws + 786432);   // [256][512] bf16, row m = b*4+s

    k_proj<<<32, 256, 0, stream>>>(hs, ipw, ipb, h0f, h1f, h0b, h1b);

    for (int s = 0; s < NSTEP; ++s) {
        int cur = s & 1, nxt = cur ^ 1;
        const float* xf  = (s == 0) ? nullptr : embed;
        const int*   ids = (s == 0) ? nullptr : tids + (s - 1);
        // layer 0
        k_gru<<<32, 256, 0, stream>>>(xf, (const bf16*)nullptr, ids,
            h0f + cur * 32768, h0b + cur * 32768, wih0, whh0, bih0, bhh0,
            h0f + nxt * 32768, h0b + nxt * 32768, (bf16*)nullptr, 0);
        // layer 1 (x = h1 just produced, internal bf16); writes hbig row b*4+s
        k_gru<<<32, 256, 0, stream>>>((const float*)nullptr, h0b + nxt * 32768, (const int*)nullptr,
            h1f + cur * 32768, h1b + cur * 32768, wih1, whh1, bih1, bhh1,
            h1f + nxt * 32768, h1b + nxt * 32768, hbig, s);
    }

    k_logits<<<(VOC + 63) / 64, 256, 0, stream>>>(hbig, outw, out);
}

// Round 3
// 444.505 us; speedup vs baseline: 1.2370x; 1.2370x over previous
//
#include <hip/hip_runtime.h>
#include <hip/hip_bf16.h>

#define B64   64
#define DH    512
#define HID   4096
#define VOC   50257
#define NSTEP 4
#define DHDH  (DH*DH)
#define NBLK_FUSED 32

typedef __attribute__((ext_vector_type(8)))  short bf16x8;   // 8 bf16 = 4 VGPRs
typedef __attribute__((ext_vector_type(4)))  float f32x4;
typedef __attribute__((ext_vector_type(16))) float f32x16;
typedef __hip_bfloat16 bf16;

__device__ __forceinline__ bf16x8 ldg8(const bf16* p) {
    return *reinterpret_cast<const bf16x8*>(p);
}
__device__ __forceinline__ short f2bf(float x) {
    bf16 h = __float2bfloat16(x);
    return *reinterpret_cast<short*>(&h);
}
__device__ __forceinline__ bf16x8 cvt8(const float* p) {
    f32x4 a = *reinterpret_cast<const f32x4*>(p);
    f32x4 b = *reinterpret_cast<const f32x4*>(p + 4);
    bf16x8 r;
    r[0] = f2bf(a[0]); r[1] = f2bf(a[1]); r[2] = f2bf(a[2]); r[3] = f2bf(a[3]);
    r[4] = f2bf(b[0]); r[5] = f2bf(b[1]); r[6] = f2bf(b[2]); r[7] = f2bf(b[3]);
    return r;
}
__device__ __forceinline__ float sigmf(float x) { return 1.f / (1.f + __expf(-x)); }

// ---------------------------------------------------------------------------
// k_prep (full grid): convert ip_w, hs, 4 GRU weight matrices to bf16; gather
// embed rows for steps 1..3 (x inputs are known upfront) as bf16.
// One 8-elem chunk per thread; grid covers exactly 700416 chunks.
// ---------------------------------------------------------------------------
__global__ __launch_bounds__(512) void k_prep(
    const float* __restrict__ hs, const float* __restrict__ ipw,
    const float* __restrict__ wi0, const float* __restrict__ wh0,
    const float* __restrict__ wi1, const float* __restrict__ wh1,
    const float* __restrict__ embed, const int* __restrict__ tids,
    bf16* __restrict__ hsb, bf16* __restrict__ ipwb,
    bf16* __restrict__ w0i, bf16* __restrict__ w0h,
    bf16* __restrict__ w1i, bf16* __restrict__ w1h,
    bf16* __restrict__ xemb)
{
    int c = blockIdx.x * 512 + threadIdx.x;
    const float* src; bf16* dst;
    if      (c < 262144) { size_t t = c;           src = ipw + t*8; dst = ipwb + t*8; }
    else if (c < 294912) { size_t t = c - 262144;  src = hs  + t*8; dst = hsb  + t*8; }
    else if (c < 393216) { size_t t = c - 294912;  src = wi0 + t*8; dst = w0i + t*8; }
    else if (c < 491520) { size_t t = c - 393216;  src = wh0 + t*8; dst = w0h + t*8; }
    else if (c < 589824) { size_t t = c - 491520;  src = wi1 + t*8; dst = w1i + t*8; }
    else if (c < 688128) { size_t t = c - 589824;  src = wh1 + t*8; dst = w1h + t*8; }
    else {
        int t = c - 688128;              // 12288 chunks = 192 rows x 64 chunks
        int r = t >> 6, j = t & 63;      // r = (s-1)*64 + b
        int s = r >> 6, b = r & 63;
        int rid = tids[b * NSTEP + s];
        src = embed + (size_t)rid * DH + j * 8;
        dst = xemb  + (size_t)r   * DH + j * 8;
    }
    *reinterpret_cast<bf16x8*>(dst) = cvt8(src);
}

// ---------------------------------------------------------------------------
// grid-wide spin barrier: one counter per phase, zeroed by hipMemsetAsync
// before launch. Agent-scope release-RMW / acquire-load; 32 blocks are
// guaranteed co-resident (32 <= 256 CUs, no occupancy limiter).
// ---------------------------------------------------------------------------
__device__ __forceinline__ void gridbar(int* bar, int phase) {
    __syncthreads();
    if (threadIdx.x == 0) {
        __threadfence();
        __hip_atomic_fetch_add(&bar[phase], 1, __ATOMIC_RELEASE, __HIP_MEMORY_SCOPE_AGENT);
        while (__hip_atomic_load(&bar[phase], __ATOMIC_ACQUIRE, __HIP_MEMORY_SCOPE_AGENT) < NBLK_FUSED)
            __builtin_amdgcn_s_sleep(2);
        __threadfence();
    }
    __syncthreads();
}

// ---------------------------------------------------------------------------
// One GRU cell (device fn). All-bf16 operands. Wave = 16 batch x 16 d tile.
// r=sig(ir+hr) z=sig(iz+hz) n=tanh(in + r*hn) h'=(1-z)n+z*h  (biases folded)
// ---------------------------------------------------------------------------
__device__ __forceinline__ void gru_cell(
    const bf16* __restrict__ xp,                       // may be null (x == 0)
    const float* __restrict__ hf, const bf16* __restrict__ hb,
    const bf16* __restrict__ wi, const bf16* __restrict__ wh,
    const float* __restrict__ bi, const float* __restrict__ bh,
    float* __restrict__ hof, bf16* __restrict__ hob,
    bf16* __restrict__ hbig, int step,
    int m0, int d0, int lr, int q)
{
    int rowb = m0 + lr;
    const bf16* hrow = hb + (size_t)rowb * DH + q * 8;
    const bf16* xrow = xp ? xp + (size_t)rowb * DH + q * 8 : nullptr;
    size_t wof = (size_t)(d0 + lr) * DH + q * 8;
    const bf16* wiR = wi + wof;
    const bf16* whR = wh + wof;

    f32x4 aR = {0,0,0,0}, aZ = {0,0,0,0}, aN = {0,0,0,0};
    f32x4 iR = {0,0,0,0}, iZ = {0,0,0,0}, iN = {0,0,0,0};
#pragma unroll 4
    for (int k0 = 0; k0 < DH; k0 += 32) {
        bf16x8 ah = ldg8(hrow + k0);
        aR = __builtin_amdgcn_mfma_f32_16x16x32_bf16(ah, ldg8(whR + k0),          aR, 0, 0, 0);
        aZ = __builtin_amdgcn_mfma_f32_16x16x32_bf16(ah, ldg8(whR + DHDH + k0),   aZ, 0, 0, 0);
        aN = __builtin_amdgcn_mfma_f32_16x16x32_bf16(ah, ldg8(whR + 2*DHDH + k0), aN, 0, 0, 0);
        if (xrow) {
            bf16x8 ax = ldg8(xrow + k0);
            iR = __builtin_amdgcn_mfma_f32_16x16x32_bf16(ax, ldg8(wiR + k0),          iR, 0, 0, 0);
            iZ = __builtin_amdgcn_mfma_f32_16x16x32_bf16(ax, ldg8(wiR + DHDH + k0),   iZ, 0, 0, 0);
            iN = __builtin_amdgcn_mfma_f32_16x16x32_bf16(ax, ldg8(wiR + 2*DHDH + k0), iN, 0, 0, 0);
        }
    }

    int d = d0 + lr;
    float bR  = bi[d] + bh[d];
    float bZ  = bi[DH + d] + bh[DH + d];
    float biN = bi[2*DH + d], bhN = bh[2*DH + d];
#pragma unroll
    for (int r = 0; r < 4; ++r) {
        int b = m0 + q * 4 + r;
        float rg = sigmf(iR[r] + aR[r] + bR);
        float zg = sigmf(iZ[r] + aZ[r] + bZ);
        float ng = tanhf(iN[r] + biN + rg * (aN[r] + bhN));
        float hp = hf[b * DH + d];
        float hv = (1.f - zg) * ng + zg * hp;
        hof[b * DH + d] = hv;
        bf16 hvb = __float2bfloat16(hv);
        hob[b * DH + d] = hvb;
        if (hbig) hbig[(size_t)(b * NSTEP + step) * DH + d] = hvb;
    }
}

// ---------------------------------------------------------------------------
// k_fused (32 blocks x 256): input proj + all 8 GRU cells with grid barriers.
// 128 waves = 4 m-tiles x 32 d-tiles.
// ---------------------------------------------------------------------------
__global__ __launch_bounds__(256) void k_fused(
    const bf16* __restrict__ hsb, const bf16* __restrict__ ipwb, const float* __restrict__ ipb,
    const bf16* __restrict__ w0i, const bf16* __restrict__ w0h,
    const float* __restrict__ bi0, const float* __restrict__ bh0,
    const bf16* __restrict__ w1i, const bf16* __restrict__ w1h,
    const float* __restrict__ bi1, const float* __restrict__ bh1,
    const bf16* __restrict__ xemb,
    float* __restrict__ h0f, float* __restrict__ h1f,
    bf16* __restrict__ h0b, bf16* __restrict__ h1b,
    bf16* __restrict__ hbig, int* __restrict__ bar)
{
    int w = threadIdx.x >> 6, lane = threadIdx.x & 63;
    int wid = blockIdx.x * 4 + w;
    int lr = lane & 15, q = lane >> 4;
    int m0 = (wid >> 5) * 16;
    int d0 = (wid & 31) * 16;

    // ---- phase 0: h0 = hs @ ip_w^T + ip_b (bf16 inputs, K=4096)
    {
        const bf16* arow = hsb  + (size_t)(m0 + lr) * HID + q * 8;
        const bf16* brow = ipwb + (size_t)(d0 + lr) * HID + q * 8;
        f32x4 acc = {0,0,0,0};
#pragma unroll 8
        for (int k0 = 0; k0 < HID; k0 += 32)
            acc = __builtin_amdgcn_mfma_f32_16x16x32_bf16(ldg8(arow + k0), ldg8(brow + k0), acc, 0, 0, 0);
        int d = d0 + lr;
        float bias = ipb[d];
#pragma unroll
        for (int r = 0; r < 4; ++r) {
            int m = m0 + q * 4 + r;
            float v = acc[r] + bias;
            int idx = m * DH + d;
            h0f[idx] = v; h1f[idx] = v;
            bf16 vb = __float2bfloat16(v);
            h0b[idx] = vb; h1b[idx] = vb;
        }
    }
    int ph = 0;
    gridbar(bar, ph++);

    // ---- 4 steps x 2 layers
    int cur0 = 0, cur1 = 0;
    for (int s = 0; s < NSTEP; ++s) {
        const bf16* xp = s ? xemb + (size_t)(s - 1) * B64 * DH : nullptr;
        gru_cell(xp, h0f + cur0 * 32768, h0b + cur0 * 32768, w0i, w0h, bi0, bh0,
                 h0f + (cur0 ^ 1) * 32768, h0b + (cur0 ^ 1) * 32768,
                 (bf16*)nullptr, 0, m0, d0, lr, q);
        cur0 ^= 1;
        gridbar(bar, ph++);
        gru_cell(h0b + cur0 * 32768, h1f + cur1 * 32768, h1b + cur1 * 32768, w1i, w1h, bi1, bh1,
                 h1f + (cur1 ^ 1) * 32768, h1b + (cur1 ^ 1) * 32768,
                 hbig, s, m0, d0, lr, q);
        cur1 ^= 1;
        if (s < NSTEP - 1) gridbar(bar, ph++);
    }
}

// ---------------------------------------------------------------------------
// k_logits: out(256x50257 f32) = Hbig(256x512 bf16) @ out_w(50257x512 f32)^T
// 32x32x16 MFMA; wave = 8 m-tiles(32) x 32 n-cols; block = 4 waves = 128 cols.
// A staged per 64-k chunk in XOR-swizzled LDS (16B groups): conflict-free.
// ---------------------------------------------------------------------------
__global__ __launch_bounds__(256) void k_logits(
    const bf16* __restrict__ hbig, const float* __restrict__ outw, float* __restrict__ out)
{
    __shared__ __align__(16) bf16 sA[256 * 64];
    int t = threadIdx.x, w = t >> 6, lane = t & 63;
    int l32 = lane & 31, e = lane >> 5;
    int n = blockIdx.x * 128 + w * 32 + l32;
    int nr = n < VOC ? n : VOC - 1;
    const float* brow = outw + (size_t)nr * DH;

    f32x16 acc[8];
#pragma unroll
    for (int i = 0; i < 8; ++i)
#pragma unroll
        for (int j = 0; j < 16; ++j) acc[i][j] = 0.f;

    for (int k0 = 0; k0 < DH; k0 += 64) {
        // stage A[0:256][k0:k0+64] -> LDS, XOR-swizzled 16B groups
#pragma unroll
        for (int i = 0; i < 8; ++i) {
            int c = i * 256 + t;
            int m = c >> 3, j = c & 7;
            *reinterpret_cast<bf16x8*>(&sA[m * 64 + ((j ^ (m & 7)) << 3)]) =
                ldg8(hbig + (size_t)m * DH + k0 + j * 8);
        }
        __syncthreads();
#pragma unroll
        for (int kk = 0; kk < 64; kk += 16) {
            bf16x8 bfrag = cvt8(brow + k0 + kk + e * 8);
            int g = (kk >> 3) + e;
#pragma unroll
            for (int mt = 0; mt < 8; ++mt) {
                int r = mt * 32 + l32;
                bf16x8 afrag = *reinterpret_cast<const bf16x8*>(
                    &sA[r * 64 + ((g ^ (r & 7)) << 3)]);
                acc[mt] = __builtin_amdgcn_mfma_f32_32x32x16_bf16(afrag, bfrag, acc[mt], 0, 0, 0);
            }
        }
        __syncthreads();
    }
    if (n < VOC) {
#pragma unroll
        for (int mt = 0; mt < 8; ++mt)
#pragma unroll
            for (int reg = 0; reg < 16; ++reg) {
                int m = mt * 32 + (reg & 3) + 8 * (reg >> 2) + 4 * e;
                out[(size_t)m * VOC + n] = acc[mt][reg];
            }
    }
}

// ---------------------------------------------------------------------------
extern "C" void kernel_launch(void* const* d_in, const int* in_sizes, int n_in,
                              void* d_out, int out_size, void* d_ws, size_t ws_size,
                              hipStream_t stream) {
    const float* hs   = (const float*)d_in[0];
    const int*   tids = (const int*)d_in[1];
    const float* ipw  = (const float*)d_in[2];
    const float* ipb  = (const float*)d_in[3];
    const float* wih0 = (const float*)d_in[4];
    const float* whh0 = (const float*)d_in[5];
    const float* bih0 = (const float*)d_in[6];
    const float* bhh0 = (const float*)d_in[7];
    const float* wih1 = (const float*)d_in[8];
    const float* whh1 = (const float*)d_in[9];
    const float* bih1 = (const float*)d_in[10];
    const float* bhh1 = (const float*)d_in[11];
    const float* embed = (const float*)d_in[12];
    const float* outw  = (const float*)d_in[13];
    float* out = (float*)d_out;

    char* ws = (char*)d_ws;
    int*  bar  = (int*) (ws + 0);          // 64 ints, memset to 0 below
    bf16* hsb  = (bf16*)(ws + 1024);       // 64x4096        (524288 B)
    bf16* ipwb = (bf16*)(ws + 525312);     // 512x4096       (4194304 B)
    bf16* w0i  = (bf16*)(ws + 4719616);    // 1536x512       (1572864 B)
    bf16* w0h  = (bf16*)(ws + 6292480);
    bf16* w1i  = (bf16*)(ws + 7865344);
    bf16* w1h  = (bf16*)(ws + 9438208);
    bf16* xemb = (bf16*)(ws + 11011072);   // 3x64x512       (196608 B)
    float* h0f = (float*)(ws + 11207680);  // [2][64x512] f32 (262144 B)
    float* h1f = (float*)(ws + 11469824);
    bf16*  h0b = (bf16*) (ws + 11731968);  // [2][64x512] bf16 (131072 B)
    bf16*  h1b = (bf16*) (ws + 11863040);
    bf16*  hbig= (bf16*) (ws + 11994112);  // 256x512 bf16, row m = b*4+s

    hipMemsetAsync(bar, 0, 256, stream);

    k_prep<<<1368, 512, 0, stream>>>(hs, ipw, wih0, whh0, wih1, whh1, embed, tids,
                                     hsb, ipwb, w0i, w0h, w1i, w1h, xemb);

    k_fused<<<NBLK_FUSED, 256, 0, stream>>>(hsb, ipwb, ipb,
                                            w0i, w0h, bih0, bhh0,
                                            w1i, w1h, bih1, bhh1,
                                            xemb, h0f, h1f, h0b, h1b, hbig, bar);

    k_logits<<<(VOC + 127) / 128, 256, 0, stream>>>(hbig, outw, out);
}